// Round 1
// baseline (245.119 us; speedup 1.0000x reference)
//
#include <hip/hip_runtime.h>
#include <math.h>

struct GW { float k31[31]; float k11[11]; float k5[5]; };

// ---------------- kp1_desc: bilinear sample of desc1 at kp1 ----------------
__global__ void kpd_kernel(const float* __restrict__ kp1,
                           const float* __restrict__ desc1,
                           float* __restrict__ okpd) {
  int k = blockIdx.x;
  int c = threadIdx.x;
  float b = kp1[k * 4 + 0];
  float y = kp1[k * 4 + 2] * 0.125f;   // /GRID_SIZE
  float x = kp1[k * 4 + 3] * 0.125f;
  float x0 = fminf(fmaxf(floorf(x), 0.f), 31.f);
  float y0 = fminf(fmaxf(floorf(y), 0.f), 31.f);
  float x1 = fminf(x0 + 1.f, 31.f);
  float y1 = fminf(y0 + 1.f, 31.f);
  float wx = x - x0;
  float wy = y - y0;
  int bi = (int)b;
  const float* dp = desc1 + ((size_t)bi * 128 + c) * 1024;
  int ix0 = (int)x0, ix1 = (int)x1, iy0 = (int)y0, iy1 = (int)y1;
  float d00 = dp[iy0 * 32 + ix0];
  float d01 = dp[iy0 * 32 + ix1];
  float d10 = dp[iy1 * 32 + ix0];
  float d11 = dp[iy1 * 32 + ix1];
  float r = d00 * (1.f - wx) * (1.f - wy) + d01 * wx * (1.f - wy)
          + d10 * (1.f - wx) * wy + d11 * wx * wy;
  okpd[k * 128 + c] = r;
}

// ---------------- conv helpers (compile-time unrolled, register-resident) ---
template <int KS>
__device__ __forceinline__ void convH(const float (&col)[32], const float* kw,
                                      float* dst /* + h*33 strided */) {
  constexpr int PAD = KS / 2;
#pragma unroll
  for (int h = 0; h < 32; ++h) {
    float a = 0.f;
#pragma unroll
    for (int j = 0; j < KS; ++j) {
      int s = h + j - PAD;
      if (s >= 0 && s < 32) a = fmaf(kw[j], col[s], a);
    }
    dst[h * 33] = a;
  }
}

template <int KS>
__device__ __forceinline__ void convW_acc(const float (&row)[32], const float* kw,
                                          float (&acc)[32]) {
  constexpr int PAD = KS / 2;
#pragma unroll
  for (int w = 0; w < 32; ++w) {
    float a = acc[w];
#pragma unroll
    for (int j = 0; j < KS; ++j) {
      int s = w + j - PAD;
      if (s >= 0 && s < 32) a = fmaf(kw[j], row[s], a);
    }
    acc[w] = a;
  }
}

// ---------------- fused main kernel: one block per (n, 8 keypoints) ---------
__global__ __launch_bounds__(256, 3) void main_kernel(
    const float* __restrict__ kp1, const float* __restrict__ desc2,
    const float* __restrict__ homo, const float* __restrict__ vism,
    const float* __restrict__ gkpd, float* __restrict__ loss_out, GW gw) {
  extern __shared__ unsigned char smem_raw[];
  float* s_tmp = (float*)smem_raw;            // [8][32][33] blur tmp / final ns
  float* s_kpd = s_tmp + 8 * 1056;            // [128][8] transposed kp descs
  float* s_kpx = s_kpd + 1024;                // 8
  float* s_kpy = s_kpx + 8;                   // 8
  float* s_red = s_kpy + 8;                   // 4
  unsigned char* s_s8 = (unsigned char*)(s_red + 4);  // [8][32][33] s mask

  const int t = threadIdx.x;
  const int n = blockIdx.x >> 7;
  const int k0 = (blockIdx.x & 127) * 8;

  // stage kp descriptors (transposed for float4 broadcast) + kp coords
#pragma unroll
  for (int j = 0; j < 4; ++j) {
    int idx = t + 256 * j;
    int c = idx >> 3, kt = idx & 7;
    s_kpd[c * 8 + kt] = gkpd[(k0 + kt) * 128 + c];
  }
  if (t < 8) {
    s_kpx[t] = kp1[(k0 + t) * 4 + 3];
    s_kpy[t] = kp1[(k0 + t) * 4 + 2];
  }
  const float h00 = homo[n * 9 + 0], h01 = homo[n * 9 + 1], h02 = homo[n * 9 + 2];
  const float h10 = homo[n * 9 + 3], h11 = homo[n * 9 + 4], h12 = homo[n * 9 + 5];
  const float h20 = homo[n * 9 + 6], h21 = homo[n * 9 + 7], h22 = homo[n * 9 + 8];
  __syncthreads();

  // ---- phase 2: s mask (u8 in LDS) + vis (registers, 4 px/thread) ----
  float vis[4];
#pragma unroll
  for (int i = 0; i < 4; ++i) {
    int px = t + 256 * i;
    int ph = px >> 5, pw = px & 31;
    float gx = (float)(pw * 8 + 4);
    float gy = (float)(ph * 8 + 4);
    float w0 = h00 * gx + h01 * gy + h02;
    float w1 = h10 * gx + h11 * gy + h12;
    float w2 = h20 * gx + h21 * gy + h22;
    float wxp = w0 / w2;
    float wyp = w1 / w2;
    float v = 1.f;
    const float* mrow = vism + ((size_t)n * 256 + ph * 8) * 256 + pw * 8;
#pragma unroll
    for (int dy = 0; dy < 8; ++dy) {
      const float4* p = (const float4*)(mrow + dy * 256);
      float4 a = p[0], bq = p[1];
      v *= a.x * a.y * a.z * a.w;
      v *= bq.x * bq.y * bq.z * bq.w;
    }
    vis[i] = v;
#pragma unroll
    for (int kt = 0; kt < 8; ++kt) {
      float dx = s_kpx[kt] - wxp;
      float dyv = s_kpy[kt] - wyp;
      float d2 = dx * dx + dyv * dyv;
      s_s8[kt * 1056 + ph * 33 + pw] = (d2 <= 56.25f) ? 1 : 0;  // (8-0.5)^2
    }
  }
  __syncthreads();

  // ---- phase 3: triple separable Gaussian blur, ns accumulated in regs ----
  const int bkt = t >> 5;
  const int l31 = t & 31;  // column index for H-pass, row index for W-pass
  float col[32];
#pragma unroll
  for (int h = 0; h < 32; ++h)
    col[h] = (float)s_s8[bkt * 1056 + h * 33 + l31];
  float nsacc[32];
#pragma unroll
  for (int w = 0; w < 32; ++w) nsacc[w] = 0.f;

  convH<31>(col, gw.k31, s_tmp + bkt * 1056 + l31);
  __syncthreads();
  {
    float row[32];
#pragma unroll
    for (int w = 0; w < 32; ++w) row[w] = s_tmp[bkt * 1056 + l31 * 33 + w];
    convW_acc<31>(row, gw.k31, nsacc);
  }
  __syncthreads();
  convH<11>(col, gw.k11, s_tmp + bkt * 1056 + l31);
  __syncthreads();
  {
    float row[32];
#pragma unroll
    for (int w = 0; w < 32; ++w) row[w] = s_tmp[bkt * 1056 + l31 * 33 + w];
    convW_acc<11>(row, gw.k11, nsacc);
  }
  __syncthreads();
  convH<5>(col, gw.k5, s_tmp + bkt * 1056 + l31);
  __syncthreads();
  {
    float row[32];
#pragma unroll
    for (int w = 0; w < 32; ++w) row[w] = s_tmp[bkt * 1056 + l31 * 33 + w];
    convW_acc<5>(row, gw.k5, nsacc);
  }
  // write final blur-sum into own row of s_tmp (only this thread read it)
#pragma unroll
  for (int w = 0; w < 32; ++w) s_tmp[bkt * 1056 + l31 * 33 + w] = nsacc[w];
  __syncthreads();

  // ---- phase 4: dot over C=128, coalesced desc2, LDS-broadcast kpd ----
  float acc[8][4];
#pragma unroll
  for (int a = 0; a < 8; ++a)
#pragma unroll
    for (int i = 0; i < 4; ++i) acc[a][i] = 0.f;
  const float* d2base = desc2 + (size_t)n * 128 * 1024 + t;
#pragma unroll 4
  for (int c = 0; c < 128; ++c) {
    const float* dp = d2base + (size_t)c * 1024;
    float v0 = dp[0], v1 = dp[256], v2 = dp[512], v3 = dp[768];
    float4 kva = *(const float4*)&s_kpd[c * 8];
    float4 kvb = *(const float4*)&s_kpd[c * 8 + 4];
    float kv[8] = {kva.x, kva.y, kva.z, kva.w, kvb.x, kvb.y, kvb.z, kvb.w};
    float v[4] = {v0, v1, v2, v3};
#pragma unroll
    for (int a = 0; a < 8; ++a)
#pragma unroll
      for (int i = 0; i < 4; ++i) acc[a][i] = fmaf(kv[a], v[i], acc[a][i]);
  }

  // ---- phase 5: hinge terms + reduction ----
  const float POSL = (float)(374.359 * 0.3);
  float lp = 0.f;
#pragma unroll
  for (int i = 0; i < 4; ++i) {
    int px = t + 256 * i;
    int ph = px >> 5, pw = px & 31;
#pragma unroll
    for (int a = 0; a < 8; ++a) {
      float sval = (float)s_s8[a * 1056 + ph * 33 + pw];
      float nsv = s_tmp[a * 1056 + ph * 33 + pw] - 3.f * sval;
      float sv = sval * vis[i];
      float nv = nsv * vis[i];
      float dot = acc[a][i];
      float pos = fmaxf(1.f - dot, 0.f);
      float neg = fmaxf(dot - 0.2f, 0.f);
      lp = fmaf(POSL * sv, pos, lp);
      lp = fmaf(nv, neg, lp);
    }
  }
#pragma unroll
  for (int off = 32; off > 0; off >>= 1) lp += __shfl_down(lp, off, 64);
  if ((t & 63) == 0) s_red[t >> 6] = lp;
  __syncthreads();
  if (t == 0) {
    float tot = (s_red[0] + s_red[1]) + (s_red[2] + s_red[3]);
    atomicAdd(loss_out, tot * (float)(1.0 / (1024.0 * 374.359)));
  }
}

// ---------------------------------------------------------------------------
extern "C" void kernel_launch(void* const* d_in, const int* in_sizes, int n_in,
                              void* d_out, int out_size, void* d_ws, size_t ws_size,
                              hipStream_t stream) {
  (void)in_sizes; (void)n_in; (void)out_size; (void)d_ws; (void)ws_size;
  const float* kp1   = (const float*)d_in[0];
  const float* desc1 = (const float*)d_in[1];
  const float* desc2 = (const float*)d_in[2];
  const float* homo  = (const float*)d_in[3];
  const float* vism  = (const float*)d_in[4];
  float* out = (float*)d_out;

  GW gw;
  auto fill = [](float* k, int ks, double sigma) {
    double sum = 0.0;
    for (int i = 0; i < ks; ++i) {
      double x = i - (ks - 1) / 2.0;
      double v = exp(-(x * x) / (2.0 * sigma * sigma));
      k[i] = (float)v;
      sum += v;
    }
    for (int i = 0; i < ks; ++i) k[i] = (float)(k[i] / sum);
  };
  fill(gw.k31, 31, 7.0);
  fill(gw.k11, 11, 4.0);
  fill(gw.k5, 5, 2.0);

  hipMemsetAsync(d_out, 0, sizeof(float), stream);  // zero the loss accumulator
  kpd_kernel<<<dim3(1024), dim3(128), 0, stream>>>(kp1, desc1, out + 1);

  constexpr int SMEM = (8 * 1056 + 1024 + 8 + 8 + 4) * 4 + 8 * 1056;  // 46416 B
  main_kernel<<<dim3(1024), dim3(256), SMEM, stream>>>(kp1, desc2, homo, vism,
                                                       out + 1, out, gw);
}

// Round 2
// 213.502 us; speedup vs baseline: 1.1481x; 1.1481x over previous
//
#include <hip/hip_runtime.h>
#include <math.h>

// ---------------- kp1_desc: bilinear sample of desc1 at kp1 ----------------
__global__ void kpd_kernel(const float* __restrict__ kp1,
                           const float* __restrict__ desc1,
                           float* __restrict__ okpd) {
  int k = blockIdx.x;
  int c = threadIdx.x;
  float b = kp1[k * 4 + 0];
  float y = kp1[k * 4 + 2] * 0.125f;   // /GRID_SIZE
  float x = kp1[k * 4 + 3] * 0.125f;
  float x0 = fminf(fmaxf(floorf(x), 0.f), 31.f);
  float y0 = fminf(fmaxf(floorf(y), 0.f), 31.f);
  float x1 = fminf(x0 + 1.f, 31.f);
  float y1 = fminf(y0 + 1.f, 31.f);
  float wx = x - x0;
  float wy = y - y0;
  int bi = (int)b;
  const float* dp = desc1 + ((size_t)bi * 128 + c) * 1024;
  int ix0 = (int)x0, ix1 = (int)x1, iy0 = (int)y0, iy1 = (int)y1;
  float d00 = dp[iy0 * 32 + ix0];
  float d01 = dp[iy0 * 32 + ix1];
  float d10 = dp[iy1 * 32 + ix0];
  float d11 = dp[iy1 * 32 + ix1];
  float r = d00 * (1.f - wx) * (1.f - wy) + d01 * wx * (1.f - wy)
          + d10 * (1.f - wx) * wy + d11 * wx * wy;
  okpd[k * 128 + c] = r;
}

// ---------------- fused main kernel: one block per (n, 8 keypoints) ---------
// s mask is ~3 active cells per (n,k); blur = sum of stamp lookups (linear
// conv of sparse mask). No dense blur, no big register arrays -> no spills.
__global__ __launch_bounds__(256, 4) void main_kernel(
    const float* __restrict__ kp1, const float* __restrict__ desc2,
    const float* __restrict__ homo, const float* __restrict__ vism,
    const float* __restrict__ gkpd, float* __restrict__ loss_out,
    float inv31sq, float inv11sq, float inv5sq) {
  __shared__ float s_kpd[1024];      // [128][8] transposed kp descriptors
  __shared__ float s_stamp[961];     // 31x31 combined gaussian stamp
  __shared__ float s_kpx[8], s_kpy[8];
  __shared__ int s_cnt[8];
  __shared__ int s_list[8][64];      // packed (ph<<5|pw) active cells per kt
  __shared__ float s_red[4];

  const int t = threadIdx.x;
  const int n = blockIdx.x >> 7;
  const int k0 = (blockIdx.x & 127) * 8;

  // ---- stage kp descriptors (transposed) + coords + stamp table ----
#pragma unroll
  for (int j = 0; j < 4; ++j) {
    int idx = t + 256 * j;
    int c = idx >> 3, kt = idx & 7;
    s_kpd[c * 8 + kt] = gkpd[(k0 + kt) * 128 + c];
  }
  if (t < 8) {
    s_kpx[t] = kp1[(k0 + t) * 4 + 3];
    s_kpy[t] = kp1[(k0 + t) * 4 + 2];
    s_cnt[t] = 0;
  }
#pragma unroll
  for (int j = 0; j < 4; ++j) {
    int idx = t + 256 * j;
    if (idx < 961) {
      int dy = idx / 31, dx = idx % 31;
      float ay = (float)(dy - 15), ax = (float)(dx - 15);
      float r2 = ay * ay + ax * ax;
      float v = expf(r2 * (-1.f / 98.f)) * inv31sq;          // sigma 7, ks31
      if (dy >= 10 && dy <= 20 && dx >= 10 && dx <= 20)
        v += expf(r2 * (-1.f / 32.f)) * inv11sq;             // sigma 4, ks11
      if (dy >= 13 && dy <= 17 && dx >= 13 && dx <= 17)
        v += expf(r2 * (-1.f / 8.f)) * inv5sq;               // sigma 2, ks5
      s_stamp[idx] = v;
    }
  }
  const float h00 = homo[n * 9 + 0], h01 = homo[n * 9 + 1], h02 = homo[n * 9 + 2];
  const float h10 = homo[n * 9 + 3], h11 = homo[n * 9 + 4], h12 = homo[n * 9 + 5];
  const float h20 = homo[n * 9 + 6], h21 = homo[n * 9 + 7], h22 = homo[n * 9 + 8];
  __syncthreads();

  // ---- phase 2: warp grid, vis, active-cell detection (4 px/thread) ----
  float vis[4];
  unsigned smask = 0;  // bit (i*8+kt): s==1 at this thread's pixel i for kp kt
#pragma unroll
  for (int i = 0; i < 4; ++i) {
    int px = t * 4 + i;
    int ph = px >> 5, pw = px & 31;
    float gx = (float)(pw * 8 + 4);
    float gy = (float)(ph * 8 + 4);
    float w0 = h00 * gx + h01 * gy + h02;
    float w1 = h10 * gx + h11 * gy + h12;
    float w2 = h20 * gx + h21 * gy + h22;
    float wxp = w0 / w2;
    float wyp = w1 / w2;
    float v = 1.f;
    const float* mrow = vism + ((size_t)n * 256 + ph * 8) * 256 + pw * 8;
#pragma unroll
    for (int dy = 0; dy < 8; ++dy) {
      const float4* p = (const float4*)(mrow + dy * 256);
      float4 a = p[0], bq = p[1];
      v *= a.x * a.y * a.z * a.w;
      v *= bq.x * bq.y * bq.z * bq.w;
    }
    vis[i] = v;
#pragma unroll
    for (int kt = 0; kt < 8; ++kt) {
      float dx = s_kpx[kt] - wxp;
      float dyv = s_kpy[kt] - wyp;
      float d2 = dx * dx + dyv * dyv;
      if (d2 <= 56.25f) {  // (8-0.5)^2
        smask |= 1u << (i * 8 + kt);
        int pos = atomicAdd(&s_cnt[kt], 1);
        if (pos < 64) s_list[kt][pos] = (ph << 5) | pw;
      }
    }
  }
  __syncthreads();

  // ---- phase 3: dot over C=128, float4 coalesced desc2, LDS broadcast ----
  float acc[8][4];
#pragma unroll
  for (int a = 0; a < 8; ++a)
#pragma unroll
    for (int i = 0; i < 4; ++i) acc[a][i] = 0.f;
  const float* d2base = desc2 + (size_t)n * 131072 + t * 4;
#pragma unroll 4
  for (int c = 0; c < 128; ++c) {
    float4 v4 = *(const float4*)(d2base + (size_t)c * 1024);
    float4 ka = *(const float4*)&s_kpd[c * 8];
    float4 kb = *(const float4*)&s_kpd[c * 8 + 4];
    float kv[8] = {ka.x, ka.y, ka.z, ka.w, kb.x, kb.y, kb.z, kb.w};
    float vv[4] = {v4.x, v4.y, v4.z, v4.w};
#pragma unroll
    for (int a = 0; a < 8; ++a)
#pragma unroll
      for (int i = 0; i < 4; ++i) acc[a][i] = fmaf(kv[a], vv[i], acc[a][i]);
  }

  // ---- phase 4: ns via stamp lookups + hinge + reduction ----
  int cnt[8];
#pragma unroll
  for (int kt = 0; kt < 8; ++kt) cnt[kt] = min(s_cnt[kt], 64);

  const float POSL = (float)(374.359 * 0.3);
  float lp = 0.f;
#pragma unroll
  for (int i = 0; i < 4; ++i) {
    int px = t * 4 + i;
    int ph = px >> 5, pw = px & 31;
#pragma unroll
    for (int kt = 0; kt < 8; ++kt) {
      float sval = (float)((smask >> (i * 8 + kt)) & 1u);
      float blur = 0.f;
      for (int j = 0; j < cnt[kt]; ++j) {   // uniform small loop (~3 iters)
        int cell = s_list[kt][j];
        int dy = ph - (cell >> 5) + 15;
        int dx = pw - (cell & 31) + 15;
        if ((unsigned)dy < 31u && (unsigned)dx < 31u)
          blur += s_stamp[dy * 31 + dx];
      }
      float nsv = blur - 3.f * sval;
      float dot = acc[kt][i];
      float pos = fmaxf(1.f - dot, 0.f);
      float neg = fmaxf(dot - 0.2f, 0.f);
      lp = fmaf(POSL * sval * vis[i], pos, lp);
      lp = fmaf(nsv * vis[i], neg, lp);
    }
  }
#pragma unroll
  for (int off = 32; off > 0; off >>= 1) lp += __shfl_down(lp, off, 64);
  if ((t & 63) == 0) s_red[t >> 6] = lp;
  __syncthreads();
  if (t == 0) {
    float tot = (s_red[0] + s_red[1]) + (s_red[2] + s_red[3]);
    atomicAdd(loss_out, tot * (float)(1.0 / (1024.0 * 374.359)));
  }
}

// ---------------------------------------------------------------------------
extern "C" void kernel_launch(void* const* d_in, const int* in_sizes, int n_in,
                              void* d_out, int out_size, void* d_ws, size_t ws_size,
                              hipStream_t stream) {
  (void)in_sizes; (void)n_in; (void)out_size; (void)d_ws; (void)ws_size;
  const float* kp1   = (const float*)d_in[0];
  const float* desc1 = (const float*)d_in[1];
  const float* desc2 = (const float*)d_in[2];
  const float* homo  = (const float*)d_in[3];
  const float* vism  = (const float*)d_in[4];
  float* out = (float*)d_out;

  // 1/S^2 normalization constants for the three separable gaussian kernels
  auto ksum = [](int ks, double sigma) {
    double sum = 0.0;
    for (int i = 0; i < ks; ++i) {
      double x = i - (ks - 1) / 2.0;
      sum += exp(-(x * x) / (2.0 * sigma * sigma));
    }
    return sum;
  };
  double s31 = ksum(31, 7.0), s11 = ksum(11, 4.0), s5 = ksum(5, 2.0);
  float inv31sq = (float)(1.0 / (s31 * s31));
  float inv11sq = (float)(1.0 / (s11 * s11));
  float inv5sq  = (float)(1.0 / (s5 * s5));

  hipMemsetAsync(d_out, 0, sizeof(float), stream);  // zero the loss accumulator
  kpd_kernel<<<dim3(1024), dim3(128), 0, stream>>>(kp1, desc1, out + 1);
  main_kernel<<<dim3(1024), dim3(256), 0, stream>>>(kp1, desc2, homo, vism,
                                                    out + 1, out,
                                                    inv31sq, inv11sq, inv5sq);
}

// Round 3
// 74.434 us; speedup vs baseline: 3.2931x; 2.8683x over previous
//
#include <hip/hip_runtime.h>
#include <math.h>

// ---------------- kp1_desc: bilinear sample of desc1 at kp1 ----------------
__global__ void kpd_kernel(const float* __restrict__ kp1,
                           const float* __restrict__ desc1,
                           float* __restrict__ okpd) {
  int k = blockIdx.x;
  int c = threadIdx.x;
  float b = kp1[k * 4 + 0];
  float y = kp1[k * 4 + 2] * 0.125f;   // /GRID_SIZE
  float x = kp1[k * 4 + 3] * 0.125f;
  float x0 = fminf(fmaxf(floorf(x), 0.f), 31.f);
  float y0 = fminf(fmaxf(floorf(y), 0.f), 31.f);
  float x1 = fminf(x0 + 1.f, 31.f);
  float y1 = fminf(y0 + 1.f, 31.f);
  float wx = x - x0;
  float wy = y - y0;
  int bi = (int)b;
  const float* dp = desc1 + ((size_t)bi * 128 + c) * 1024;
  int ix0 = (int)x0, ix1 = (int)x1, iy0 = (int)y0, iy1 = (int)y1;
  float d00 = dp[iy0 * 32 + ix0];
  float d01 = dp[iy0 * 32 + ix1];
  float d10 = dp[iy1 * 32 + ix0];
  float d11 = dp[iy1 * 32 + ix1];
  float r = d00 * (1.f - wx) * (1.f - wy) + d01 * wx * (1.f - wy)
          + d10 * (1.f - wx) * wy + d11 * wx * wy;
  okpd[k * 128 + c] = r;
}

// ---------------- vis grid: product over each 8x8 patch --------------------
// vism (N,1,256,256) -> vis (N,32,32). 8 blocks (one per n) x 256 threads.
__global__ void vis_kernel(const float* __restrict__ vism,
                           float* __restrict__ visg) {
  int n = blockIdx.x;
  int t = threadIdx.x;
#pragma unroll
  for (int i = 0; i < 4; ++i) {
    int cell = t + 256 * i;
    int ph = cell >> 5, pw = cell & 31;
    const float* mrow = vism + ((size_t)n * 256 + ph * 8) * 256 + pw * 8;
    float v = 1.f;
#pragma unroll
    for (int dy = 0; dy < 8; ++dy) {
      const float4* p = (const float4*)(mrow + dy * 256);
      float4 a = p[0], bq = p[1];
      v *= a.x * a.y * a.z * a.w;
      v *= bq.x * bq.y * bq.z * bq.w;
    }
    visg[n * 1024 + cell] = v;
  }
}

// ---------------- fused main kernel: one block per (n, 8 keypoints) ---------
// s mask is ~3 active cells per (n,k); blur = sum of stamp lookups (linear
// conv of sparse mask). vis comes precomputed from ws. XCD swizzle: n = bid&7
// so each XCD keeps one n's desc2 slice (512 KB) L2-resident.
__global__ __launch_bounds__(256, 4) void main_kernel(
    const float* __restrict__ kp1, const float* __restrict__ desc2,
    const float* __restrict__ homo, const float* __restrict__ visg,
    const float* __restrict__ gkpd, float* __restrict__ loss_out,
    float inv31sq, float inv11sq, float inv5sq) {
  __shared__ float s_kpd[1024];      // [128][8] transposed kp descriptors
  __shared__ float s_stamp[961];     // 31x31 combined gaussian stamp
  __shared__ float s_kpx[8], s_kpy[8];
  __shared__ int s_cnt[8];
  __shared__ int s_list[8][64];      // packed (ph<<5|pw) active cells per kt
  __shared__ float s_red[4];

  const int t = threadIdx.x;
  const int bid = blockIdx.x;
  const int n = bid & 7;             // XCD-locality swizzle
  const int k0 = (bid >> 3) * 8;

  // ---- stage kp descriptors (coalesced read, LDS transpose) + stamp ----
#pragma unroll
  for (int j = 0; j < 4; ++j) {
    int idx = t + 256 * j;
    int kt = idx >> 7, c = idx & 127;
    s_kpd[c * 8 + kt] = gkpd[(k0 + kt) * 128 + c];
  }
  if (t < 8) {
    s_kpx[t] = kp1[(k0 + t) * 4 + 3];
    s_kpy[t] = kp1[(k0 + t) * 4 + 2];
    s_cnt[t] = 0;
  }
#pragma unroll
  for (int j = 0; j < 4; ++j) {
    int idx = t + 256 * j;
    if (idx < 961) {
      int dy = idx / 31, dx = idx % 31;
      float ay = (float)(dy - 15), ax = (float)(dx - 15);
      float r2 = ay * ay + ax * ax;
      float v = expf(r2 * (-1.f / 98.f)) * inv31sq;          // sigma 7, ks31
      if (dy >= 10 && dy <= 20 && dx >= 10 && dx <= 20)
        v += expf(r2 * (-1.f / 32.f)) * inv11sq;             // sigma 4, ks11
      if (dy >= 13 && dy <= 17 && dx >= 13 && dx <= 17)
        v += expf(r2 * (-1.f / 8.f)) * inv5sq;               // sigma 2, ks5
      s_stamp[idx] = v;
    }
  }
  const float h00 = homo[n * 9 + 0], h01 = homo[n * 9 + 1], h02 = homo[n * 9 + 2];
  const float h10 = homo[n * 9 + 3], h11 = homo[n * 9 + 4], h12 = homo[n * 9 + 5];
  const float h20 = homo[n * 9 + 6], h21 = homo[n * 9 + 7], h22 = homo[n * 9 + 8];
  __syncthreads();

  // ---- phase 2: warp grid, vis (precomputed), active-cell detection ----
  float vis[4];
  unsigned smask = 0;  // bit (i*8+kt): s==1 at this thread's pixel i for kp kt
#pragma unroll
  for (int i = 0; i < 4; ++i) {
    int px = t * 4 + i;
    int ph = px >> 5, pw = px & 31;
    float gx = (float)(pw * 8 + 4);
    float gy = (float)(ph * 8 + 4);
    float w0 = h00 * gx + h01 * gy + h02;
    float w1 = h10 * gx + h11 * gy + h12;
    float w2 = h20 * gx + h21 * gy + h22;
    float wxp = w0 / w2;
    float wyp = w1 / w2;
    vis[i] = visg[n * 1024 + px];
#pragma unroll
    for (int kt = 0; kt < 8; ++kt) {
      float dx = s_kpx[kt] - wxp;
      float dyv = s_kpy[kt] - wyp;
      float d2 = dx * dx + dyv * dyv;
      if (d2 <= 56.25f) {  // (8-0.5)^2
        smask |= 1u << (i * 8 + kt);
        int pos = atomicAdd(&s_cnt[kt], 1);
        if (pos < 64) s_list[kt][pos] = (ph << 5) | pw;
      }
    }
  }
  __syncthreads();

  // ---- phase 3: dot over C=128, float4 coalesced desc2, LDS broadcast ----
  float acc[8][4];
#pragma unroll
  for (int a = 0; a < 8; ++a)
#pragma unroll
    for (int i = 0; i < 4; ++i) acc[a][i] = 0.f;
  const float* d2base = desc2 + (size_t)n * 131072 + t * 4;
#pragma unroll 4
  for (int c = 0; c < 128; ++c) {
    float4 v4 = *(const float4*)(d2base + (size_t)c * 1024);
    float4 ka = *(const float4*)&s_kpd[c * 8];
    float4 kb = *(const float4*)&s_kpd[c * 8 + 4];
    float kv[8] = {ka.x, ka.y, ka.z, ka.w, kb.x, kb.y, kb.z, kb.w};
    float vv[4] = {v4.x, v4.y, v4.z, v4.w};
#pragma unroll
    for (int a = 0; a < 8; ++a)
#pragma unroll
      for (int i = 0; i < 4; ++i) acc[a][i] = fmaf(kv[a], vv[i], acc[a][i]);
  }

  // ---- phase 4: ns via stamp lookups + hinge + reduction ----
  int cnt[8];
#pragma unroll
  for (int kt = 0; kt < 8; ++kt) cnt[kt] = min(s_cnt[kt], 64);

  const float POSL = (float)(374.359 * 0.3);
  float lp = 0.f;
#pragma unroll
  for (int i = 0; i < 4; ++i) {
    int px = t * 4 + i;
    int ph = px >> 5, pw = px & 31;
#pragma unroll
    for (int kt = 0; kt < 8; ++kt) {
      float sval = (float)((smask >> (i * 8 + kt)) & 1u);
      float blur = 0.f;
      for (int j = 0; j < cnt[kt]; ++j) {   // uniform small loop (~3 iters)
        int cell = s_list[kt][j];
        int dy = ph - (cell >> 5) + 15;
        int dx = pw - (cell & 31) + 15;
        if ((unsigned)dy < 31u && (unsigned)dx < 31u)
          blur += s_stamp[dy * 31 + dx];
      }
      float nsv = blur - 3.f * sval;
      float dot = acc[kt][i];
      float pos = fmaxf(1.f - dot, 0.f);
      float neg = fmaxf(dot - 0.2f, 0.f);
      lp = fmaf(POSL * sval * vis[i], pos, lp);
      lp = fmaf(nsv * vis[i], neg, lp);
    }
  }
#pragma unroll
  for (int off = 32; off > 0; off >>= 1) lp += __shfl_down(lp, off, 64);
  if ((t & 63) == 0) s_red[t >> 6] = lp;
  __syncthreads();
  if (t == 0) {
    float tot = (s_red[0] + s_red[1]) + (s_red[2] + s_red[3]);
    atomicAdd(loss_out, tot * (float)(1.0 / (1024.0 * 374.359)));
  }
}

// ---------------------------------------------------------------------------
extern "C" void kernel_launch(void* const* d_in, const int* in_sizes, int n_in,
                              void* d_out, int out_size, void* d_ws, size_t ws_size,
                              hipStream_t stream) {
  (void)in_sizes; (void)n_in; (void)out_size; (void)ws_size;
  const float* kp1   = (const float*)d_in[0];
  const float* desc1 = (const float*)d_in[1];
  const float* desc2 = (const float*)d_in[2];
  const float* homo  = (const float*)d_in[3];
  const float* vism  = (const float*)d_in[4];
  float* out = (float*)d_out;
  float* visg = (float*)d_ws;   // 8*1024 floats = 32 KB

  // 1/S^2 normalization constants for the three separable gaussian kernels
  auto ksum = [](int ks, double sigma) {
    double sum = 0.0;
    for (int i = 0; i < ks; ++i) {
      double x = i - (ks - 1) / 2.0;
      sum += exp(-(x * x) / (2.0 * sigma * sigma));
    }
    return sum;
  };
  double s31 = ksum(31, 7.0), s11 = ksum(11, 4.0), s5 = ksum(5, 2.0);
  float inv31sq = (float)(1.0 / (s31 * s31));
  float inv11sq = (float)(1.0 / (s11 * s11));
  float inv5sq  = (float)(1.0 / (s5 * s5));

  hipMemsetAsync(d_out, 0, sizeof(float), stream);  // zero the loss accumulator
  vis_kernel<<<dim3(8), dim3(256), 0, stream>>>(vism, visg);
  kpd_kernel<<<dim3(1024), dim3(128), 0, stream>>>(kp1, desc1, out + 1);
  main_kernel<<<dim3(1024), dim3(256), 0, stream>>>(kp1, desc2, homo, visg,
                                                    out + 1, out,
                                                    inv31sq, inv11sq, inv5sq);
}